// Round 6
// baseline (11655.231 us; speedup 1.0000x reference)
//
#include <hip/hip_runtime.h>

#define HID   1024
#define TLEN  512
#define VOC   128
#define NR    32          // reset-gate blocks: 32 cols each (r, rh)
#define NZ    32          // update blocks: 32 cols each (z, h_tilde, h_new)
#define NO    8           // out-head blocks: 16 vocab cols each
#define NBLK  (NR + NZ + NO)
#define LDSK  1032        // padded LDS row stride (16B-aligned rows)
#define HBUF  (64 * HID)  // one h buffer (elements)
#define NHB   8           // h buffer rotation depth

typedef __bf16 bf16_t;
typedef __attribute__((ext_vector_type(8))) __bf16 bf16x8;
typedef __attribute__((ext_vector_type(4))) float  f32x4;
typedef __attribute__((ext_vector_type(4))) unsigned uint4v;

__device__ __forceinline__ float sigmoid_fast(float x) {
  return 1.0f / (1.0f + __expf(-x));
}
__device__ __forceinline__ float tanh_fast(float x) {
  float e = __expf(-2.0f * x);
  return (1.0f - e) / (1.0f + e);
}

union PairU { bf16_t b[2]; unsigned u; };

// h/rh coherence protocol: WRITE via agent-scope relaxed atomic stores
// (write-around: data lands at the MALL, no L2 allocate); READ via
// NON-TEMPORAL plain loads (no L1/L2 allocate => can never hit a stale line,
// always served from the MALL; fully coalesced global_load_dwordx4 nt).
// => no fences anywhere, no atomic-load serialization.
__device__ __forceinline__ bf16x8 ld_nt16(const bf16_t* p) {
  union { uint4v u; bf16x8 b; } c;
  c.u = __builtin_nontemporal_load((const uint4v*)p);
  return c.b;
}
__device__ __forceinline__ PairU ld_nt4(const bf16_t* p) {
  PairU c;
  c.u = __builtin_nontemporal_load((const unsigned*)p);
  return c;
}
__device__ __forceinline__ void st_pair(bf16_t* p, float f0, float f1) {
  PairU c;
  c.b[0] = (bf16_t)f0;
  c.b[1] = (bf16_t)f1;
  __hip_atomic_store((unsigned*)p, c.u, __ATOMIC_RELAXED, __HIP_MEMORY_SCOPE_AGENT);
}

// wave 0 polls 32 packed flags (coalesced, relaxed); other waves park at the
// barrier. No acquire fence needed (see protocol above).
__device__ __forceinline__ void wait32(const unsigned* flags, unsigned tgt) {
  if ((threadIdx.x >> 6) == 0) {
    const int lane = threadIdx.x & 63;
    for (;;) {
      unsigned g = tgt;
      if (lane < 32)
        g = __hip_atomic_load(&flags[lane], __ATOMIC_RELAXED, __HIP_MEMORY_SCOPE_AGENT);
      if (__all(g >= tgt)) break;
      __builtin_amdgcn_s_sleep(1);
    }
  }
  __syncthreads();
}

// combined wait: rfl[0..32) >= tgt AND ofl[0..8) >= otgt
__device__ __forceinline__ void wait_rf_of(const unsigned* rfl, const unsigned* ofl,
                                           unsigned tgt, unsigned otgt) {
  if ((threadIdx.x >> 6) == 0) {
    const int lane = threadIdx.x & 63;
    for (;;) {
      bool ok = true;
      if (lane < 32)
        ok = __hip_atomic_load(&rfl[lane], __ATOMIC_RELAXED, __HIP_MEMORY_SCOPE_AGENT) >= tgt;
      else if (lane < 40)
        ok = __hip_atomic_load(&ofl[lane - 32], __ATOMIC_RELAXED, __HIP_MEMORY_SCOPE_AGENT) >= otgt;
      if (__all(ok)) break;
      __builtin_amdgcn_s_sleep(1);
    }
  }
  __syncthreads();
}

// publish: __syncthreads drains every wave's stores (vmcnt(0) before
// s_barrier => write-around stores are at the MALL), then one relaxed flag store.
__device__ __forceinline__ void publish(unsigned* f, unsigned v) {
  __syncthreads();
  if (threadIdx.x == 0)
    __hip_atomic_store(f, v, __ATOMIC_RELAXED, __HIP_MEMORY_SCOPE_AGENT);
}

// Flag semantics: hfl[zb] = number of h slots published by ZH block zb
// (slot s readable when all hfl >= s+1). rfl[rb] = steps of rh published.
// ofl[ob] = out-head steps completed (h_t consumed).
__global__ void __launch_bounds__(256)
gru_nt(const int* __restrict__ X,
       const float* __restrict__ Wr_x, const float* __restrict__ Wr_h, const float* __restrict__ b_r,
       const float* __restrict__ Wz_x, const float* __restrict__ Wz_h, const float* __restrict__ b_z,
       const float* __restrict__ Wh_x, const float* __restrict__ Wh_h, const float* __restrict__ b_h,
       const float* __restrict__ W_o,  const float* __restrict__ b_o,
       float* __restrict__ out,
       bf16_t* __restrict__ h0, bf16_t* __restrict__ rh_bf,
       unsigned* __restrict__ flags)
{
  __shared__ __align__(16) bf16_t Wbuf[2 * 32 * LDSK];  // 132KB

  unsigned* hfl = flags;        // [0,32)   published by ZH blocks
  unsigned* rfl = flags + 64;   // [64,96)  published by R blocks
  unsigned* ofl = flags + 128;  // [128,136) published by out heads

  const int blk  = blockIdx.x;
  const int tid  = threadIdx.x;
  const int lane = tid & 63;
  const int wv   = tid >> 6;     // wave -> batch tile [wv*16, +16)
  const int n16  = lane & 15;    // A-row(batch) / B-col / D-col within tile
  const int q    = lane >> 4;    // k-subchunk / D-row quad

  const int aoff = (wv * 16 + n16) * HID + q * 8;  // A-frag offset in h/rh

  int bi[4];
#pragma unroll
  for (int i = 0; i < 4; ++i) bi[i] = wv * 16 + q * 4 + i;

  if (blk < NR) {
    // ============ R block: 32 cols of r -> rh ==============================
    const int c0 = blk * 32;
    // column remap: LDS tile0 row p <- col 2p, tile1 row p <- col 2p+1,
    // so lane n16's two D values are ADJACENT cols (one 4B store).
    for (int idx = tid; idx < 32 * HID; idx += 256) {
      int n = idx & 31, k = idx >> 5;
      Wbuf[((n & 1) * 16 + (n >> 1)) * LDSK + k] = (bf16_t)Wr_h[k * HID + c0 + n];
    }
    __syncthreads();

    const int j0 = c0 + 2 * n16;            // even col; j0+1 is the odd one
    const float br0 = b_r[j0], br1 = b_r[j0 + 1];
    const bf16_t* w0 = &Wbuf[n16 * LDSK + q * 8];
    const bf16_t* w1 = &Wbuf[(16 + n16) * LDSK + q * 8];

    for (int t = 0; t < TLEN; ++t) {
      wait32(hfl, (unsigned)(t + 1));
      const bf16_t* hslot = h0 + (t & (NHB - 1)) * HBUF;
      int xb[4]; float gx0[4], gx1[4];
#pragma unroll
      for (int i = 0; i < 4; ++i) {
        xb[i]  = X[bi[i] * TLEN + t];
        gx0[i] = Wr_x[xb[i] * HID + j0];
        gx1[i] = Wr_x[xb[i] * HID + j0 + 1];
      }
      const bf16_t* hrow = hslot + aoff;
      f32x4 a0 = {0.f,0.f,0.f,0.f}, a1 = {0.f,0.f,0.f,0.f};
#pragma unroll 8
      for (int kk = 0; kk < 32; ++kk) {
        bf16x8 a  = ld_nt16(hrow + kk * 32);
        bf16x8 b0 = *reinterpret_cast<const bf16x8*>(w0 + kk * 32);
        bf16x8 b1 = *reinterpret_cast<const bf16x8*>(w1 + kk * 32);
        a0 = __builtin_amdgcn_mfma_f32_16x16x32_bf16(a, b0, a0, 0, 0, 0);
        a1 = __builtin_amdgcn_mfma_f32_16x16x32_bf16(a, b1, a1, 0, 0, 0);
      }
#pragma unroll
      for (int i = 0; i < 4; ++i) {
        int b = bi[i];
        float r0 = sigmoid_fast(a0[i] + br0 + gx0[i]);
        float r1 = sigmoid_fast(a1[i] + br1 + gx1[i]);
        PairU hp = ld_nt4(hslot + b * HID + j0);
        st_pair(rh_bf + b * HID + j0, r0 * (float)hp.b[0], r1 * (float)hp.b[1]);
      }
      publish(&rfl[blk], (unsigned)(t + 1));
    }
  } else if (blk < NR + NZ) {
    // ============ ZH block: 32 cols of z, h_tilde, h_new ===================
    const int zb = blk - NR;
    const int c0 = zb * 32;
    for (int idx = tid; idx < 32 * HID; idx += 256) {
      int n = idx & 31, k = idx >> 5;
      int r = (n & 1) * 16 + (n >> 1);
      Wbuf[r * LDSK + k]             = (bf16_t)Wz_h[k * HID + c0 + n];
      Wbuf[32 * LDSK + r * LDSK + k] = (bf16_t)Wh_h[k * HID + c0 + n];
    }

    const int j0 = c0 + 2 * n16;
    // in-kernel zero-init of h slot 0 (MUST go through the atomic-store path:
    // a memset would plant cached lines that nt loads could later hit stale)
#pragma unroll
    for (int i = 0; i < 4; ++i)
      st_pair(h0 + bi[i] * HID + j0, 0.f, 0.f);
    publish(&hfl[zb], 1u);   // h slot 0 ready (also covers the LDS staging)

    const float bz0 = b_z[j0], bz1 = b_z[j0 + 1];
    const float bh0 = b_h[j0], bh1 = b_h[j0 + 1];
    const bf16_t* wz0 = &Wbuf[n16 * LDSK + q * 8];
    const bf16_t* wz1 = &Wbuf[(16 + n16) * LDSK + q * 8];
    const bf16_t* wh0 = &Wbuf[32 * LDSK + n16 * LDSK + q * 8];
    const bf16_t* wh1 = &Wbuf[32 * LDSK + (16 + n16) * LDSK + q * 8];
    const bf16_t* rhrow = rh_bf + aoff;

    f32x4 hm0 = {0.f,0.f,0.f,0.f}, hm1 = {0.f,0.f,0.f,0.f};  // fp32 h master

    for (int t = 0; t < TLEN; ++t) {
      // ---- z phase (needs only h(t); overlaps R's work) ----
      wait32(hfl, (unsigned)(t + 1));
      int xb[4]; float gz0[4], gz1[4], gh0[4], gh1[4];
#pragma unroll
      for (int i = 0; i < 4; ++i) {
        xb[i]  = X[bi[i] * TLEN + t];
        gz0[i] = Wz_x[xb[i] * HID + j0];
        gz1[i] = Wz_x[xb[i] * HID + j0 + 1];
        gh0[i] = Wh_x[xb[i] * HID + j0];
        gh1[i] = Wh_x[xb[i] * HID + j0 + 1];
      }
      const bf16_t* hrow = h0 + (t & (NHB - 1)) * HBUF + aoff;
      f32x4 az0 = {0.f,0.f,0.f,0.f}, az1 = {0.f,0.f,0.f,0.f};
#pragma unroll 8
      for (int kk = 0; kk < 32; ++kk) {
        bf16x8 a  = ld_nt16(hrow + kk * 32);
        bf16x8 b0 = *reinterpret_cast<const bf16x8*>(wz0 + kk * 32);
        bf16x8 b1 = *reinterpret_cast<const bf16x8*>(wz1 + kk * 32);
        az0 = __builtin_amdgcn_mfma_f32_16x16x32_bf16(a, b0, az0, 0, 0, 0);
        az1 = __builtin_amdgcn_mfma_f32_16x16x32_bf16(a, b1, az1, 0, 0, 0);
      }
      f32x4 z0, z1;
#pragma unroll
      for (int i = 0; i < 4; ++i) {
        z0[i] = sigmoid_fast(az0[i] + bz0 + gz0[i]);
        z1[i] = sigmoid_fast(az1[i] + bz1 + gz1[i]);
      }

      // ---- h_tilde phase (needs full rh(t); WAR guard vs out heads) ----
      unsigned otgt = (t >= NHB - 1) ? (unsigned)(t - (NHB - 1)) : 0u;
      wait_rf_of(rfl, ofl, (unsigned)(t + 1), otgt);
      f32x4 ah0 = {0.f,0.f,0.f,0.f}, ah1 = {0.f,0.f,0.f,0.f};
#pragma unroll 8
      for (int kk = 0; kk < 32; ++kk) {
        bf16x8 a  = ld_nt16(rhrow + kk * 32);
        bf16x8 b0 = *reinterpret_cast<const bf16x8*>(wh0 + kk * 32);
        bf16x8 b1 = *reinterpret_cast<const bf16x8*>(wh1 + kk * 32);
        ah0 = __builtin_amdgcn_mfma_f32_16x16x32_bf16(a, b0, ah0, 0, 0, 0);
        ah1 = __builtin_amdgcn_mfma_f32_16x16x32_bf16(a, b1, ah1, 0, 0, 0);
      }
      bf16_t* hnext = h0 + ((t + 1) & (NHB - 1)) * HBUF;
#pragma unroll
      for (int i = 0; i < 4; ++i) {
        int b = bi[i];
        float ht0 = tanh_fast(ah0[i] + bh0 + gh0[i]);
        float ht1 = tanh_fast(ah1[i] + bh1 + gh1[i]);
        float hn0 = z0[i] * hm0[i] + (1.f - z0[i]) * ht0;
        float hn1 = z1[i] * hm1[i] + (1.f - z1[i]) * ht1;
        hm0[i] = hn0; hm1[i] = hn1;
        st_pair(hnext + b * HID + j0, hn0, hn1);
      }
      publish(&hfl[zb], (unsigned)(t + 2));  // slot t+1 published
    }
  } else {
    // ============ out head: out[t-1] = h_t @ W_o + b_o =====================
    const int ob = blk - NR - NZ;
    const int c0 = ob * 16;
    for (int idx = tid; idx < 16 * HID; idx += 256) {
      int n = idx & 15, k = idx >> 4;
      Wbuf[n * LDSK + k] = (bf16_t)W_o[k * VOC + c0 + n];
    }
    __syncthreads();

    const int v = c0 + n16;
    const float bos = b_o[v];
    const bf16_t* w0 = &Wbuf[n16 * LDSK + q * 8];

    for (int t = 1; t <= TLEN; ++t) {
      wait32(hfl, (unsigned)(t + 1));   // h slot t readable
      const bf16_t* hrow = h0 + (t & (NHB - 1)) * HBUF + aoff;
      f32x4 acc = {0.f,0.f,0.f,0.f};
#pragma unroll 8
      for (int kk = 0; kk < 32; ++kk) {
        bf16x8 a = ld_nt16(hrow + kk * 32);
        bf16x8 b = *reinterpret_cast<const bf16x8*>(w0 + kk * 32);
        acc = __builtin_amdgcn_mfma_f32_16x16x32_bf16(a, b, acc, 0, 0, 0);
      }
#pragma unroll
      for (int i = 0; i < 4; ++i) {
        int b = bi[i];
        out[(b * TLEN + (t - 1)) * VOC + v] = acc[i] + bos;  // cached store
      }
      publish(&ofl[ob], (unsigned)t);  // h_t reads drained by publish's barrier
    }
  }
}

extern "C" void kernel_launch(void* const* d_in, const int* in_sizes, int n_in,
                              void* d_out, int out_size, void* d_ws, size_t ws_size,
                              hipStream_t stream) {
  const int*   X    = (const int*)d_in[0];
  const float* Wr_x = (const float*)d_in[1];
  const float* Wr_h = (const float*)d_in[2];
  const float* b_r  = (const float*)d_in[3];
  const float* Wz_x = (const float*)d_in[4];
  const float* Wz_h = (const float*)d_in[5];
  const float* b_z  = (const float*)d_in[6];
  const float* Wh_x = (const float*)d_in[7];
  const float* Wh_h = (const float*)d_in[8];
  const float* b_h  = (const float*)d_in[9];
  const float* W_o  = (const float*)d_in[10];
  const float* b_o  = (const float*)d_in[11];

  char* ws = (char*)d_ws;
  // layout: [flags 4KB | h 8 x 128KB | rh 128KB]
  unsigned* flags = (unsigned*)ws;
  bf16_t*   h0    = (bf16_t*)(ws + 4096);
  bf16_t*   rh_bf = (bf16_t*)(ws + 4096 + NHB * HBUF * sizeof(bf16_t));

  // zero ONLY the flags; h slot 0 is zeroed in-kernel via the atomic-store
  // path (a cached memset would leave lines that nt loads could hit stale)
  hipMemsetAsync(ws, 0, 4096, stream);

  gru_nt<<<NBLK, 256, 0, stream>>>(
      X, Wr_x, Wr_h, b_r, Wz_x, Wz_h, b_z, Wh_x, Wh_h, b_h, W_o, b_o,
      (float*)d_out, h0, rh_bf, flags);
}

// Round 7
// 9184.245 us; speedup vs baseline: 1.2690x; 1.2690x over previous
//
#include <hip/hip_runtime.h>

#define HID   1024
#define TLEN  512
#define VOC   128
#define NRZ   32          // r+z blocks: 32 cols each (r-matmul, z-matmul)
#define NH    32          // h blocks: 32 cols each (h_tilde + update)
#define NO    8           // out-head blocks: 16 vocab cols each
#define NBLK  (NRZ + NH + NO)
#define LDSK  1032        // padded LDS row stride
#define HBUF  (64 * HID)  // one h buffer (elements)
#define NHB   8           // h buffer rotation depth

typedef __bf16 bf16_t;
typedef __attribute__((ext_vector_type(8))) __bf16 bf16x8;
typedef __attribute__((ext_vector_type(4))) float  f32x4;

__device__ __forceinline__ float sigmoid_fast(float x) {
  return 1.0f / (1.0f + __expf(-x));
}
__device__ __forceinline__ float tanh_fast(float x) {
  float e = __expf(-2.0f * x);
  return (1.0f - e) / (1.0f + e);
}

union PairU { bf16_t b[2]; unsigned u; };
union ZPair { float f[2]; unsigned long long u; };

// Protocol (validated r4): bulk h/rh via PLAIN CACHED loads/stores (intra-XCD
// L2 dedup of the broadcast) + acquire fence (inv) after flag observe +
// release flag store (wbl2) at publish. z is small -> sc1 atomics, no fence.

__device__ __forceinline__ void wait_fence(const unsigned* flags, int n, unsigned tgt) {
  if ((threadIdx.x >> 6) == 0) {
    const int lane = threadIdx.x & 63;
    for (;;) {
      unsigned g = tgt;
      if (lane < n)
        g = __hip_atomic_load(&flags[lane], __ATOMIC_RELAXED, __HIP_MEMORY_SCOPE_AGENT);
      if (__all(g >= tgt)) break;
      __builtin_amdgcn_s_sleep(1);
    }
    __builtin_amdgcn_fence(__ATOMIC_ACQUIRE, "agent");
  }
  __syncthreads();
}

__device__ __forceinline__ void wait_nofence(const unsigned* flags, int n, unsigned tgt) {
  if ((threadIdx.x >> 6) == 0) {
    const int lane = threadIdx.x & 63;
    for (;;) {
      unsigned g = tgt;
      if (lane < n)
        g = __hip_atomic_load(&flags[lane], __ATOMIC_RELAXED, __HIP_MEMORY_SCOPE_AGENT);
      if (__all(g >= tgt)) break;
      __builtin_amdgcn_s_sleep(1);
    }
  }
  __syncthreads();
}

// rfl[0..32) >= tgt (lanes 0..31) AND ofl[0..8) >= otgt (lanes 32..39)
__device__ __forceinline__ void wait_rh_out(const unsigned* rfl, const unsigned* ofl,
                                            unsigned tgt, unsigned otgt) {
  if ((threadIdx.x >> 6) == 0) {
    const int lane = threadIdx.x & 63;
    for (;;) {
      bool ok = true;
      if (lane < 32)
        ok = __hip_atomic_load(&rfl[lane], __ATOMIC_RELAXED, __HIP_MEMORY_SCOPE_AGENT) >= tgt;
      else if (lane < 40)
        ok = __hip_atomic_load(&ofl[lane - 32], __ATOMIC_RELAXED, __HIP_MEMORY_SCOPE_AGENT) >= otgt;
      if (__all(ok)) break;
      __builtin_amdgcn_s_sleep(1);
    }
    __builtin_amdgcn_fence(__ATOMIC_ACQUIRE, "agent");
  }
  __syncthreads();
}

__device__ __forceinline__ void publish_rel(unsigned* f, unsigned v) {
  __syncthreads();
  if (threadIdx.x == 0)
    __hip_atomic_store(f, v, __ATOMIC_RELEASE, __HIP_MEMORY_SCOPE_AGENT);
}
__device__ __forceinline__ void publish_rlx(unsigned* f, unsigned v) {
  __syncthreads();  // drains vmcnt -> sc1 z-stores are at the MALL
  if (threadIdx.x == 0)
    __hip_atomic_store(f, v, __ATOMIC_RELAXED, __HIP_MEMORY_SCOPE_AGENT);
}

#define MFMA(a, b, c) __builtin_amdgcn_mfma_f32_16x16x32_bf16((a), (b), (c), 0, 0, 0)

__global__ void __launch_bounds__(256)
gru_rz(const int* __restrict__ X,
       const float* __restrict__ Wr_x, const float* __restrict__ Wr_h, const float* __restrict__ b_r,
       const float* __restrict__ Wz_x, const float* __restrict__ Wz_h, const float* __restrict__ b_z,
       const float* __restrict__ Wh_x, const float* __restrict__ Wh_h, const float* __restrict__ b_h,
       const float* __restrict__ W_o,  const float* __restrict__ b_o,
       float* __restrict__ out,
       bf16_t* __restrict__ h0, bf16_t* __restrict__ rh_bf, float* __restrict__ z_f32,
       unsigned* __restrict__ flags)
{
  __shared__ __align__(16) bf16_t Wbuf[2 * 32 * LDSK];  // 132KB (RZ); H/O use less

  unsigned* hfl = flags;        // [0,32)  by H blocks: h slots published
  unsigned* rfl = flags + 32;   // [32,64) by RZ: rh(t) published
  unsigned* zfl = flags + 64;   // [64,96) by RZ: z(t) published
  unsigned* ofl = flags + 96;   // [96,104) by out heads: h_t consumed

  const int blk  = blockIdx.x;
  const int tid  = threadIdx.x;
  const int lane = tid & 63;
  const int wv   = tid >> 6;     // wave -> batch tile [wv*16, +16)
  const int n16  = lane & 15;
  const int q    = lane >> 4;

  const int aoff = (wv * 16 + n16) * HID + q * 8;

  int bi[4];
#pragma unroll
  for (int i = 0; i < 4; ++i) bi[i] = wv * 16 + q * 4 + i;

  if (blk < NRZ) {
    // ============ RZ block: 32 cols of r (critical) then z (shadow) ========
    const int c0 = blk * 32;
    for (int idx = tid; idx < 32 * HID; idx += 256) {
      int n = idx & 31, k = idx >> 5;
      int r = (n & 1) * 16 + (n >> 1);   // col interleave: lane's 2 cols adjacent
      Wbuf[r * LDSK + k]               = (bf16_t)Wr_h[k * HID + c0 + n];
      Wbuf[32 * LDSK + r * LDSK + k]   = (bf16_t)Wz_h[k * HID + c0 + n];
    }
    __syncthreads();

    const int j0 = c0 + 2 * n16;
    const float br0 = b_r[j0], br1 = b_r[j0 + 1];
    const float bz0 = b_z[j0], bz1 = b_z[j0 + 1];
    const bf16_t* wr0 = &Wbuf[n16 * LDSK + q * 8];
    const bf16_t* wr1 = &Wbuf[(16 + n16) * LDSK + q * 8];
    const bf16_t* wz0 = &Wbuf[32 * LDSK + n16 * LDSK + q * 8];
    const bf16_t* wz1 = &Wbuf[32 * LDSK + (16 + n16) * LDSK + q * 8];

    for (int t = 0; t < TLEN; ++t) {
      // gather prefetch (read-only data; safe before the acquire, hidden by poll)
      float gr0[4], gr1[4], gz0[4], gz1[4];
#pragma unroll
      for (int i = 0; i < 4; ++i) {
        int xb = X[bi[i] * TLEN + t];
        gr0[i] = Wr_x[xb * HID + j0];
        gr1[i] = Wr_x[xb * HID + j0 + 1];
        gz0[i] = Wz_x[xb * HID + j0];
        gz1[i] = Wz_x[xb * HID + j0 + 1];
      }
      wait_fence(hfl, NH, (unsigned)t);
      const bf16_t* hslot = h0 + (t & (NHB - 1)) * HBUF;
      const bf16_t* hrow  = hslot + aoff;
      // burst-load ALL A-fragments (1 latency exposure, 32 loads in flight)
      bf16x8 areg[32];
#pragma unroll
      for (int kk = 0; kk < 32; ++kk)
        areg[kk] = *reinterpret_cast<const bf16x8*>(hrow + kk * 32);
      f32x4 a0 = {0.f,0.f,0.f,0.f}, a1 = {0.f,0.f,0.f,0.f};
#pragma unroll
      for (int kk = 0; kk < 32; ++kk) {
        bf16x8 w0 = *reinterpret_cast<const bf16x8*>(wr0 + kk * 32);
        bf16x8 w1 = *reinterpret_cast<const bf16x8*>(wr1 + kk * 32);
        a0 = MFMA(areg[kk], w0, a0);
        a1 = MFMA(areg[kk], w1, a1);
      }
#pragma unroll
      for (int i = 0; i < 4; ++i) {
        int b = bi[i];
        float r0 = sigmoid_fast(a0[i] + br0 + gr0[i]);
        float r1 = sigmoid_fast(a1[i] + br1 + gr1[i]);
        PairU hp = *reinterpret_cast<const PairU*>(hslot + b * HID + j0);
        PairU c;
        c.b[0] = (bf16_t)(r0 * (float)hp.b[0]);
        c.b[1] = (bf16_t)(r1 * (float)hp.b[1]);
        *reinterpret_cast<PairU*>(rh_bf + b * HID + j0) = c;
      }
      publish_rel(&rfl[blk], (unsigned)(t + 1));

      // ---- z phase: reuses areg (h already in registers), off critical path
      f32x4 c0v = {0.f,0.f,0.f,0.f}, c1v = {0.f,0.f,0.f,0.f};
#pragma unroll
      for (int kk = 0; kk < 32; ++kk) {
        bf16x8 w0 = *reinterpret_cast<const bf16x8*>(wz0 + kk * 32);
        bf16x8 w1 = *reinterpret_cast<const bf16x8*>(wz1 + kk * 32);
        c0v = MFMA(areg[kk], w0, c0v);
        c1v = MFMA(areg[kk], w1, c1v);
      }
#pragma unroll
      for (int i = 0; i < 4; ++i) {
        ZPair zp;
        zp.f[0] = sigmoid_fast(c0v[i] + bz0 + gz0[i]);
        zp.f[1] = sigmoid_fast(c1v[i] + bz1 + gz1[i]);
        __hip_atomic_store((unsigned long long*)(z_f32 + bi[i] * HID + j0), zp.u,
                           __ATOMIC_RELAXED, __HIP_MEMORY_SCOPE_AGENT);
      }
      publish_rlx(&zfl[blk], (unsigned)(t + 1));
    }
  } else if (blk < NRZ + NH) {
    // ============ H block: 32 cols of h_tilde + update =====================
    const int hb = blk - NRZ;
    const int c0 = hb * 32;
    for (int idx = tid; idx < 32 * HID; idx += 256) {
      int n = idx & 31, k = idx >> 5;
      int r = (n & 1) * 16 + (n >> 1);
      Wbuf[r * LDSK + k] = (bf16_t)Wh_h[k * HID + c0 + n];
    }
    __syncthreads();

    const int j0 = c0 + 2 * n16;
    const float bh0 = b_h[j0], bh1 = b_h[j0 + 1];
    const bf16_t* wh0 = &Wbuf[n16 * LDSK + q * 8];
    const bf16_t* wh1 = &Wbuf[(16 + n16) * LDSK + q * 8];
    const bf16_t* rhrow = rh_bf + aoff;

    f32x4 hm0 = {0.f,0.f,0.f,0.f}, hm1 = {0.f,0.f,0.f,0.f};  // fp32 h master

    for (int t = 0; t < TLEN; ++t) {
      float gh0[4], gh1[4];
#pragma unroll
      for (int i = 0; i < 4; ++i) {
        int xb = X[bi[i] * TLEN + t];
        gh0[i] = Wh_x[xb * HID + j0];
        gh1[i] = Wh_x[xb * HID + j0 + 1];
      }
      unsigned otgt = (t + 1 >= NHB) ? (unsigned)(t + 2 - NHB) : 0u;  // WAR vs out
      wait_rh_out(rfl, ofl, (unsigned)(t + 1), otgt);
      bf16x8 areg[32];
#pragma unroll
      for (int kk = 0; kk < 32; ++kk)
        areg[kk] = *reinterpret_cast<const bf16x8*>(rhrow + kk * 32);
      f32x4 ah0 = {0.f,0.f,0.f,0.f}, ah1 = {0.f,0.f,0.f,0.f};
#pragma unroll
      for (int kk = 0; kk < 32; ++kk) {
        bf16x8 w0 = *reinterpret_cast<const bf16x8*>(wh0 + kk * 32);
        bf16x8 w1 = *reinterpret_cast<const bf16x8*>(wh1 + kk * 32);
        ah0 = MFMA(areg[kk], w0, ah0);
        ah1 = MFMA(areg[kk], w1, ah1);
      }
      wait_nofence(zfl, NRZ, (unsigned)(t + 1));  // z via sc1, usually ready
      bf16_t* hnext = h0 + ((t + 1) & (NHB - 1)) * HBUF;
#pragma unroll
      for (int i = 0; i < 4; ++i) {
        ZPair zp;
        zp.u = __hip_atomic_load((const unsigned long long*)(z_f32 + bi[i] * HID + j0),
                                 __ATOMIC_RELAXED, __HIP_MEMORY_SCOPE_AGENT);
        float ht0 = tanh_fast(ah0[i] + bh0 + gh0[i]);
        float ht1 = tanh_fast(ah1[i] + bh1 + gh1[i]);
        float hn0 = zp.f[0] * hm0[i] + (1.f - zp.f[0]) * ht0;
        float hn1 = zp.f[1] * hm1[i] + (1.f - zp.f[1]) * ht1;
        hm0[i] = hn0; hm1[i] = hn1;
        PairU c; c.b[0] = (bf16_t)hn0; c.b[1] = (bf16_t)hn1;
        *reinterpret_cast<PairU*>(hnext + bi[i] * HID + j0) = c;
      }
      publish_rel(&hfl[hb], (unsigned)(t + 1));
    }
  } else {
    // ============ out head: out[t-1] = h_t @ W_o + b_o =====================
    const int ob = blk - NRZ - NH;
    const int c0 = ob * 16;
    for (int idx = tid; idx < 16 * HID; idx += 256) {
      int n = idx & 15, k = idx >> 4;
      Wbuf[n * LDSK + k] = (bf16_t)W_o[k * VOC + c0 + n];
    }
    __syncthreads();

    const int v = c0 + n16;
    const float bos = b_o[v];
    const bf16_t* w0 = &Wbuf[n16 * LDSK + q * 8];

    for (int t = 1; t <= TLEN; ++t) {
      wait_fence(hfl, NH, (unsigned)t);
      const bf16_t* hrow = h0 + (t & (NHB - 1)) * HBUF + aoff;
      bf16x8 areg[32];
#pragma unroll
      for (int kk = 0; kk < 32; ++kk)
        areg[kk] = *reinterpret_cast<const bf16x8*>(hrow + kk * 32);
      f32x4 acc = {0.f,0.f,0.f,0.f};
#pragma unroll
      for (int kk = 0; kk < 32; ++kk) {
        bf16x8 b = *reinterpret_cast<const bf16x8*>(w0 + kk * 32);
        acc = MFMA(areg[kk], b, acc);
      }
#pragma unroll
      for (int i = 0; i < 4; ++i) {
        int b = bi[i];
        out[(b * TLEN + (t - 1)) * VOC + v] = acc[i] + bos;
      }
      publish_rel(&ofl[ob], (unsigned)t);  // loads retired (acc consumed them)
    }
  }
}

extern "C" void kernel_launch(void* const* d_in, const int* in_sizes, int n_in,
                              void* d_out, int out_size, void* d_ws, size_t ws_size,
                              hipStream_t stream) {
  const int*   X    = (const int*)d_in[0];
  const float* Wr_x = (const float*)d_in[1];
  const float* Wr_h = (const float*)d_in[2];
  const float* b_r  = (const float*)d_in[3];
  const float* Wz_x = (const float*)d_in[4];
  const float* Wz_h = (const float*)d_in[5];
  const float* b_z  = (const float*)d_in[6];
  const float* Wh_x = (const float*)d_in[7];
  const float* Wh_h = (const float*)d_in[8];
  const float* b_h  = (const float*)d_in[9];
  const float* W_o  = (const float*)d_in[10];
  const float* b_o  = (const float*)d_in[11];

  char* ws = (char*)d_ws;
  // layout: [flags 4KB | h 8 x 128KB | rh 128KB | z 256KB]
  unsigned* flags = (unsigned*)ws;
  bf16_t*   h0    = (bf16_t*)(ws + 4096);
  bf16_t*   rh_bf = (bf16_t*)(ws + 4096 + NHB * HBUF * sizeof(bf16_t));
  float*    z_f32 = (float*)(ws + 4096 + (NHB + 1) * HBUF * sizeof(bf16_t));

  // zero flags + h slot 0 (h(0)=0); rh/z/slots 1..7 are written before read
  hipMemsetAsync(ws, 0, 4096 + HBUF * sizeof(bf16_t), stream);

  gru_rz<<<NBLK, 256, 0, stream>>>(
      X, Wr_x, Wr_h, b_r, Wz_x, Wz_h, b_z, Wh_x, Wh_h, b_h, W_o, b_o,
      (float*)d_out, h0, rh_bf, z_f32, flags);
}

// Round 8
// 8456.053 us; speedup vs baseline: 1.3783x; 1.0861x over previous
//
#include <hip/hip_runtime.h>

#define HID   1024
#define TLEN  512
#define VOC   128
#define NBLK  256         // = #CUs; 1 block/CU (132KB LDS) -> all co-resident
#define NW    32          // worker team: all blocks of one XCD
#define NO    2           // out-head blocks: 64 vocab cols each
#define LDSK  1032        // padded LDS row stride
#define HBUF  (64 * HID)  // one h buffer (elements)
#define OD    16          // out-ring depth

typedef __bf16 bf16_t;
typedef __attribute__((ext_vector_type(8))) __bf16 bf16x8;
typedef __attribute__((ext_vector_type(4))) float  f32x4;
typedef __attribute__((ext_vector_type(2))) float  f32x2;
typedef __attribute__((ext_vector_type(4))) unsigned uint4v;

__device__ __forceinline__ float sigmoid_fast(float x) {
  return 1.0f / (1.0f + __expf(-x));
}
__device__ __forceinline__ float tanh_fast(float x) {
  float e = __expf(-2.0f * x);
  return (1.0f - e) / (1.0f + e);
}

union PairU { bf16_t b[2]; unsigned u; };

// L1-only invalidate (no sc bits): local to this CU, no fabric traffic.
// Safe+sufficient for intra-XCD sharing: producer stores are in the shared,
// coherent per-XCD L2 after the vmcnt(0) drain in __syncthreads.
__device__ __forceinline__ void l1_inv() {
  asm volatile("buffer_inv" ::: "memory");
}

// ---- cross-XCD path (h -> out-heads only): sc1 write-around stores,
// non-temporal reads (no cache ever holds a copy; r6-validated).
__device__ __forceinline__ void st_sc1(bf16_t* p, float f0, float f1) {
  PairU c; c.b[0] = (bf16_t)f0; c.b[1] = (bf16_t)f1;
  __hip_atomic_store((unsigned*)p, c.u, __ATOMIC_RELAXED, __HIP_MEMORY_SCOPE_AGENT);
}
__device__ __forceinline__ bf16x8 ld_nt16(const bf16_t* p) {
  union { uint4v u; bf16x8 b; } c;
  c.u = __builtin_nontemporal_load((const uint4v*)p);
  return c.b;
}

// wave 0 polls n packed flags (relaxed agent = MALL); others park at barrier.
__device__ __forceinline__ void poll(const unsigned* flags, int n, unsigned tgt) {
  if ((threadIdx.x >> 6) == 0) {
    const int lane = threadIdx.x & 63;
    for (;;) {
      unsigned g = tgt;
      if (lane < n)
        g = __hip_atomic_load(&flags[lane], __ATOMIC_RELAXED, __HIP_MEMORY_SCOPE_AGENT);
      if (__all(g >= tgt)) break;
      __builtin_amdgcn_s_sleep(1);
    }
  }
  __syncthreads();
}

// rfl[0..NW) >= tgt AND ofl[0..NO) >= otgt
__device__ __forceinline__ void poll_rf_of(const unsigned* rfl, const unsigned* ofl,
                                           unsigned tgt, unsigned otgt) {
  if ((threadIdx.x >> 6) == 0) {
    const int lane = threadIdx.x & 63;
    for (;;) {
      bool ok = true;
      if (lane < NW)
        ok = __hip_atomic_load(&rfl[lane], __ATOMIC_RELAXED, __HIP_MEMORY_SCOPE_AGENT) >= tgt;
      else if (lane < NW + NO)
        ok = __hip_atomic_load(&ofl[lane - NW], __ATOMIC_RELAXED, __HIP_MEMORY_SCOPE_AGENT) >= otgt;
      if (__all(ok)) break;
      __builtin_amdgcn_s_sleep(1);
    }
  }
  __syncthreads();
}

// __syncthreads drains all waves' stores (vmcnt(0) -> cached stores are in the
// shared XCD L2, sc1 stores are at the MALL), then one relaxed flag store.
__device__ __forceinline__ void publish(unsigned* f, unsigned v) {
  __syncthreads();
  if (threadIdx.x == 0)
    __hip_atomic_store(f, v, __ATOMIC_RELAXED, __HIP_MEMORY_SCOPE_AGENT);
}

#define MFMA(a, b, c) __builtin_amdgcn_mfma_f32_16x16x32_bf16((a), (b), (c), 0, 0, 0)

__global__ void __launch_bounds__(256, 1)
gru_xcd(const int* __restrict__ X,
        const float* __restrict__ Wr_x, const float* __restrict__ Wr_h, const float* __restrict__ b_r,
        const float* __restrict__ Wz_x, const float* __restrict__ Wz_h, const float* __restrict__ b_z,
        const float* __restrict__ Wh_x, const float* __restrict__ Wh_h, const float* __restrict__ b_h,
        const float* __restrict__ W_o,  const float* __restrict__ b_o,
        float* __restrict__ out,
        bf16_t* __restrict__ hring, bf16_t* __restrict__ rh_bf,
        bf16_t* __restrict__ oring, bf16_t* __restrict__ wz_bf,
        unsigned* __restrict__ flags)
{
  __shared__ __align__(16) bf16_t Wbuf[2 * 32 * LDSK];  // 132KB
  __shared__ int s_role;

  unsigned* hfl    = flags;        // [0,32)   h slots published (count)
  unsigned* rfl    = flags + 64;   // [64,96)  rh(t) published
  unsigned* ofl    = flags + 128;  // [128,130) out-head progress
  unsigned* cnt    = flags + 192;  // [192,200) per-XCD claim counters
  unsigned* winner = flags + 200;  // 0 = unset, else xcd+1
  unsigned* ocnt   = flags + 204;  // out-head claim counter

  const int tid  = threadIdx.x;
  const int lane = tid & 63;
  const int wv   = tid >> 6;
  const int n16  = lane & 15;
  const int q    = lane >> 4;
  const int aoff = (wv * 16 + n16) * HID + q * 8;

  int bi[4];
#pragma unroll
  for (int i = 0; i < 4; ++i) bi[i] = wv * 16 + q * 4 + i;

  // ---------- self-organize: first XCD to seat 32 blocks = worker team ------
  if (tid == 0) {
    unsigned xcc;
    asm volatile("s_getreg_b32 %0, hwreg(HW_REG_XCC_ID)" : "=s"(xcc));
    xcc &= 7u;
    unsigned idx = __hip_atomic_fetch_add(&cnt[xcc], 1u, __ATOMIC_RELAXED, __HIP_MEMORY_SCOPE_AGENT);
    if (idx == NW - 1) {
      unsigned exp = 0u;
      __hip_atomic_compare_exchange_strong(winner, &exp, xcc + 1u,
          __ATOMIC_RELAXED, __ATOMIC_RELAXED, __HIP_MEMORY_SCOPE_AGENT);
    }
    unsigned w;
    do {
      w = __hip_atomic_load(winner, __ATOMIC_RELAXED, __HIP_MEMORY_SCOPE_AGENT);
      __builtin_amdgcn_s_sleep(1);
    } while (w == 0u);   // guaranteed: 256 blocks over 8 XCDs -> some XCD hits 32
    if (xcc == w - 1u && idx < NW) {
      s_role = (int)idx;
    } else {
      unsigned o = __hip_atomic_fetch_add(ocnt, 1u, __ATOMIC_RELAXED, __HIP_MEMORY_SCOPE_AGENT);
      s_role = (o < NO) ? (NW + (int)o) : -1;
    }
  }
  __syncthreads();
  const int role = s_role;
  if (role < 0) return;

  if (role < NW) {
    // ============ worker (winning XCD): 32 cols of r, z, h_tilde ==========
    const int s  = role;
    const int c0 = s * 32;
    // LDS: Wr (rows 0..31), Wh (rows 32..63); col-interleave (lane's 2 cols adjacent)
    for (int idx = tid; idx < 32 * HID; idx += 256) {
      int n = idx & 31, k = idx >> 5;
      int r = (n & 1) * 16 + (n >> 1);
      Wbuf[r * LDSK + k]             = (bf16_t)Wr_h[k * HID + c0 + n];
      Wbuf[32 * LDSK + r * LDSK + k] = (bf16_t)Wh_h[k * HID + c0 + n];
    }
    // one-time: convert own Wz slice to bf16 in ws (stays in this XCD's L2)
    bf16_t* wzs = wz_bf + s * (32 * 1024);
    for (int idx = tid; idx < 32 * HID; idx += 256) {
      int n = idx & 31, k = idx >> 5;
      int r = (n & 1) * 16 + (n >> 1);
      wzs[r * 1024 + k] = (bf16_t)Wz_h[k * HID + c0 + n];
    }

    const int j0 = c0 + 2 * n16;
    // zero own slice of h slot 0 (cached stores; drained by publish)
#pragma unroll
    for (int i = 0; i < 4; ++i) {
      PairU zz; zz.b[0] = (bf16_t)0.f; zz.b[1] = (bf16_t)0.f;
      *reinterpret_cast<PairU*>(hring + bi[i] * HID + j0) = zz;
    }
    publish(&hfl[s], 1u);   // h slot 0 ready (barrier also covers LDS staging)

    const float br0 = b_r[j0], br1 = b_r[j0 + 1];
    const float bz0 = b_z[j0], bz1 = b_z[j0 + 1];
    const float bh0 = b_h[j0], bh1 = b_h[j0 + 1];
    const bf16_t* wr0 = &Wbuf[n16 * LDSK + q * 8];
    const bf16_t* wr1 = &Wbuf[(16 + n16) * LDSK + q * 8];
    const bf16_t* wh0 = &Wbuf[32 * LDSK + n16 * LDSK + q * 8];
    const bf16_t* wh1 = &Wbuf[32 * LDSK + (16 + n16) * LDSK + q * 8];
    const bf16_t* wz0 = wzs + n16 * 1024 + q * 8;
    const bf16_t* wz1 = wzs + (16 + n16) * 1024 + q * 8;
    const bf16_t* rhrow = rh_bf + aoff;

    f32x4 hm0 = {0.f,0.f,0.f,0.f}, hm1 = {0.f,0.f,0.f,0.f};  // fp32 h master

    for (int t = 0; t < TLEN; ++t) {
      // gather prefetch (read-only; refetched from L2 after L1 inv, cheap)
      float gr0[4], gr1[4], gz0[4], gz1[4], gh0[4], gh1[4];
#pragma unroll
      for (int i = 0; i < 4; ++i) {
        int xb = X[bi[i] * TLEN + t];
        gr0[i] = Wr_x[xb * HID + j0]; gr1[i] = Wr_x[xb * HID + j0 + 1];
        gz0[i] = Wz_x[xb * HID + j0]; gz1[i] = Wz_x[xb * HID + j0 + 1];
        gh0[i] = Wh_x[xb * HID + j0]; gh1[i] = Wh_x[xb * HID + j0 + 1];
      }
      // ---- r phase ----
      poll(hfl, NW, (unsigned)(t + 1));
      l1_inv();
      const bf16_t* hslot = hring + (t & 1) * HBUF;
      const bf16_t* hrow  = hslot + aoff;
      bf16x8 areg[32];
#pragma unroll
      for (int kk = 0; kk < 32; ++kk)
        areg[kk] = *reinterpret_cast<const bf16x8*>(hrow + kk * 32);
      f32x4 aR0 = {0.f,0.f,0.f,0.f}, aR1 = {0.f,0.f,0.f,0.f};
#pragma unroll
      for (int kk = 0; kk < 32; ++kk) {
        bf16x8 w0 = *reinterpret_cast<const bf16x8*>(wr0 + kk * 32);
        bf16x8 w1 = *reinterpret_cast<const bf16x8*>(wr1 + kk * 32);
        aR0 = MFMA(areg[kk], w0, aR0);
        aR1 = MFMA(areg[kk], w1, aR1);
      }
#pragma unroll
      for (int i = 0; i < 4; ++i) {
        float r0 = sigmoid_fast(aR0[i] + br0 + gr0[i]);
        float r1 = sigmoid_fast(aR1[i] + br1 + gr1[i]);
        PairU hp = *reinterpret_cast<const PairU*>(hslot + bi[i] * HID + j0);
        PairU c;
        c.b[0] = (bf16_t)(r0 * (float)hp.b[0]);
        c.b[1] = (bf16_t)(r1 * (float)hp.b[1]);
        *reinterpret_cast<PairU*>(rh_bf + bi[i] * HID + j0) = c;  // cached, local L2
      }
      publish(&rfl[s], (unsigned)(t + 1));

      // ---- z phase (shadow of other workers' r; reuses areg, streams wz) ----
      f32x4 aZ0 = {0.f,0.f,0.f,0.f}, aZ1 = {0.f,0.f,0.f,0.f};
#pragma unroll
      for (int kk = 0; kk < 32; ++kk) {
        bf16x8 w0 = *reinterpret_cast<const bf16x8*>(wz0 + kk * 32);
        bf16x8 w1 = *reinterpret_cast<const bf16x8*>(wz1 + kk * 32);
        aZ0 = MFMA(areg[kk], w0, aZ0);
        aZ1 = MFMA(areg[kk], w1, aZ1);
      }
      f32x4 z0, z1;
#pragma unroll
      for (int i = 0; i < 4; ++i) {
        z0[i] = sigmoid_fast(aZ0[i] + bz0 + gz0[i]);
        z1[i] = sigmoid_fast(aZ1[i] + bz1 + gz1[i]);
      }

      // ---- h_tilde phase ----
      unsigned otgt = (t > OD - 1) ? (unsigned)(t + 1 - OD) : 0u;  // oring WAR
      poll_rf_of(rfl, ofl, (unsigned)(t + 1), otgt);
      l1_inv();
      bf16x8 breg[32];
#pragma unroll
      for (int kk = 0; kk < 32; ++kk)
        breg[kk] = *reinterpret_cast<const bf16x8*>(rhrow + kk * 32);
      f32x4 aH0 = {0.f,0.f,0.f,0.f}, aH1 = {0.f,0.f,0.f,0.f};
#pragma unroll
      for (int kk = 0; kk < 32; ++kk) {
        bf16x8 w0 = *reinterpret_cast<const bf16x8*>(wh0 + kk * 32);
        bf16x8 w1 = *reinterpret_cast<const bf16x8*>(wh1 + kk * 32);
        aH0 = MFMA(breg[kk], w0, aH0);
        aH1 = MFMA(breg[kk], w1, aH1);
      }
      bf16_t* hnext = hring + ((t + 1) & 1) * HBUF;
      bf16_t* onext = oring + ((t + 1) % OD) * HBUF;
#pragma unroll
      for (int i = 0; i < 4; ++i) {
        float ht0 = tanh_fast(aH0[i] + bh0 + gh0[i]);
        float ht1 = tanh_fast(aH1[i] + bh1 + gh1[i]);
        float hn0 = z0[i] * hm0[i] + (1.f - z0[i]) * ht0;
        float hn1 = z1[i] * hm1[i] + (1.f - z1[i]) * ht1;
        hm0[i] = hn0; hm1[i] = hn1;
        PairU c; c.b[0] = (bf16_t)hn0; c.b[1] = (bf16_t)hn1;
        *reinterpret_cast<PairU*>(hnext + bi[i] * HID + j0) = c;  // local L2
        st_sc1(onext + bi[i] * HID + j0, hn0, hn1);               // MALL (out path)
      }
      publish(&hfl[s], (unsigned)(t + 2));
    }
    // clean this XCD's dirty L2 lines so the next replay (possibly a different
    // winner XCD) never races two dirty copies at the MALL.
    __builtin_amdgcn_fence(__ATOMIC_RELEASE, "agent");
  } else {
    // ============ out head: 64 vocab cols; out[t-1] = h_t @ W_o + b_o ======
    const int ob  = role - NW;
    const int c0o = ob * 64;
    for (int idx = tid; idx < 64 * HID; idx += 256) {
      int n = idx & 63, k = idx >> 6;
      int g = n >> 5, m = n & 31;
      int r = g * 32 + (m & 1) * 16 + (m >> 1);
      Wbuf[r * LDSK + k] = (bf16_t)W_o[k * VOC + c0o + n];
    }
    __syncthreads();

    float bo[2][2];
#pragma unroll
    for (int g = 0; g < 2; ++g) {
      bo[g][0] = b_o[c0o + 32 * g + 2 * n16];
      bo[g][1] = b_o[c0o + 32 * g + 2 * n16 + 1];
    }
    const bf16_t* wo[2][2];
#pragma unroll
    for (int g = 0; g < 2; ++g)
#pragma unroll
      for (int h = 0; h < 2; ++h)
        wo[g][h] = &Wbuf[(g * 32 + h * 16 + n16) * LDSK + q * 8];

    for (int t = 1; t <= TLEN; ++t) {
      poll(hfl, NW, (unsigned)(t + 1));   // h slot t in the out-ring
      const bf16_t* hrow = oring + (t % OD) * HBUF + aoff;
      bf16x8 areg[32];
#pragma unroll
      for (int kk = 0; kk < 32; ++kk)
        areg[kk] = ld_nt16(hrow + kk * 32);
      f32x4 acc[2][2];
#pragma unroll
      for (int g = 0; g < 2; ++g)
#pragma unroll
        for (int h = 0; h < 2; ++h)
          acc[g][h] = (f32x4){0.f, 0.f, 0.f, 0.f};
#pragma unroll
      for (int kk = 0; kk < 32; ++kk) {
#pragma unroll
        for (int g = 0; g < 2; ++g) {
          bf16x8 w0 = *reinterpret_cast<const bf16x8*>(wo[g][0] + kk * 32);
          bf16x8 w1 = *reinterpret_cast<const bf16x8*>(wo[g][1] + kk * 32);
          acc[g][0] = MFMA(areg[kk], w0, acc[g][0]);
          acc[g][1] = MFMA(areg[kk], w1, acc[g][1]);
        }
      }
#pragma unroll
      for (int g = 0; g < 2; ++g) {
        const int j0 = c0o + 32 * g + 2 * n16;
#pragma unroll
        for (int i = 0; i < 4; ++i) {
          f32x2 v = {acc[g][0][i] + bo[g][0], acc[g][1][i] + bo[g][1]};
          *reinterpret_cast<f32x2*>(&out[(bi[i] * TLEN + (t - 1)) * VOC + j0]) = v;
        }
      }
      publish(&ofl[ob], (unsigned)t);  // NT reads retired (consumed by MFMA)
    }
  }
}

extern "C" void kernel_launch(void* const* d_in, const int* in_sizes, int n_in,
                              void* d_out, int out_size, void* d_ws, size_t ws_size,
                              hipStream_t stream) {
  const int*   X    = (const int*)d_in[0];
  const float* Wr_x = (const float*)d_in[1];
  const float* Wr_h = (const float*)d_in[2];
  const float* b_r  = (const float*)d_in[3];
  const float* Wz_x = (const float*)d_in[4];
  const float* Wz_h = (const float*)d_in[5];
  const float* b_z  = (const float*)d_in[6];
  const float* Wh_x = (const float*)d_in[7];
  const float* Wh_h = (const float*)d_in[8];
  const float* b_h  = (const float*)d_in[9];
  const float* W_o  = (const float*)d_in[10];
  const float* b_o  = (const float*)d_in[11];

  char* ws = (char*)d_ws;
  // layout: [flags 4KB | hring 2x128KB | rh 128KB | oring 16x128KB | wz 2MB]
  unsigned* flags = (unsigned*)ws;
  bf16_t*   hring = (bf16_t*)(ws + 4096);
  bf16_t*   rh_bf = (bf16_t*)(ws + 4096 + 2 * HBUF * sizeof(bf16_t));
  bf16_t*   oring = (bf16_t*)(ws + 4096 + 3 * HBUF * sizeof(bf16_t));
  bf16_t*   wz_bf = (bf16_t*)(ws + 4096 + (3 + OD) * HBUF * sizeof(bf16_t));

  // zero flags + claim state; all data buffers are written before read
  hipMemsetAsync(ws, 0, 4096, stream);

  gru_xcd<<<NBLK, 256, 0, stream>>>(
      X, Wr_x, Wr_h, b_r, Wz_x, Wz_h, b_z, Wh_x, Wh_h, b_h, W_o, b_o,
      (float*)d_out, hring, rh_bf, oring, wz_bf, flags);
}